// Round 1
// baseline (993.133 us; speedup 1.0000x reference)
//
#include <hip/hip_runtime.h>
#include <math.h>

#define NTOK 16384      // b*n = 8*2048
#define NPB  2048       // tokens per batch
#define DDIM 1024
#define NEXP 64
#define CAP  80
#define SOUT 83886080LL // NTOK*NEXP*CAP

// workspace layout (bytes)
#define OFF_IDX1   0
#define OFF_IDX2   (OFF_IDX1  + NTOK*4)
#define OFF_KEEP2  (OFF_IDX2  + NTOK*4)
#define OFF_POS1   (OFF_KEEP2 + NTOK*4)
#define OFF_POS2   (OFF_POS1  + NTOK*4)
#define OFF_G1     (OFF_POS2  + NTOK*4)
#define OFF_G2     (OFF_G1    + NTOK*4)
#define OFF_SUMG   (OFF_G2    + NTOK*4)
#define OFF_CNT1   (OFF_SUMG  + 512*4)

// K1: fused logits GEMM (64 tokens x 64 experts per block, K=1024) +
// softmax + top1/top2 + renorm + keep2 + per-(b,e) raw-gate sums for loss.
__global__ __launch_bounds__(256) void k_gate(
    const float* __restrict__ x, const float* __restrict__ w,
    const float* __restrict__ noise,
    int* __restrict__ idx1, int* __restrict__ idx2, int* __restrict__ keep2,
    float* __restrict__ g1o, float* __restrict__ g2o,
    float* __restrict__ sumG)
{
    __shared__ float xs[32][68];   // x tile, transposed: xs[k][token]
    __shared__ float wl[32][64];   // w tile: wl[k][expert]
    __shared__ float lg[64][65];   // logits tile
    __shared__ float sG[4][64];    // per-wave raw-gate sums

    const int tid  = threadIdx.x;
    const int tok0 = blockIdx.x * 64;
    const int tx = tid & 15, ty = tid >> 4;   // expert quad / token quad
    float acc[4][4] = {{0.f}};

    const float* xb = x + (size_t)tok0 * DDIM;

    for (int k0 = 0; k0 < DDIM; k0 += 32) {
        #pragma unroll
        for (int r = 0; r < 2; ++r) {
            int f = tid + r * 256;            // 0..511 (float4 slots)
            int t = f >> 3, c = f & 7;
            float4 v = *(const float4*)(xb + (size_t)t * DDIM + k0 + 4 * c);
            xs[4*c+0][t] = v.x; xs[4*c+1][t] = v.y;
            xs[4*c+2][t] = v.z; xs[4*c+3][t] = v.w;
            // w tile rows k0..k0+31 are 2048 contiguous floats
            ((float4*)wl)[f] = ((const float4*)(w + (size_t)k0 * NEXP))[f];
        }
        __syncthreads();
        #pragma unroll
        for (int k = 0; k < 32; ++k) {
            float4 a  = *(const float4*)&xs[k][ty * 4];
            float4 bb = *(const float4*)&wl[k][tx * 4];
            float av[4] = {a.x, a.y, a.z, a.w};
            float bv[4] = {bb.x, bb.y, bb.z, bb.w};
            #pragma unroll
            for (int i = 0; i < 4; ++i)
                #pragma unroll
                for (int j = 0; j < 4; ++j)
                    acc[i][j] = fmaf(av[i], bv[j], acc[i][j]);
        }
        __syncthreads();
    }

    // park logits in LDS
    #pragma unroll
    for (int i = 0; i < 4; ++i)
        #pragma unroll
        for (int j = 0; j < 4; ++j)
            lg[ty * 4 + i][tx * 4 + j] = acc[i][j];
    __syncthreads();

    // softmax + top2 per token: lane == expert, wave handles 16 tokens
    const int lane = tid & 63;
    const int wv   = tid >> 6;
    const int b    = tok0 / NPB;
    float gsum_acc = 0.f;

    for (int it = 0; it < 16; ++it) {
        int t = wv * 16 + it;
        float v = lg[t][lane];

        // argmax (first-index tie-break)
        float m = v; int mi = lane;
        #pragma unroll
        for (int off = 32; off; off >>= 1) {
            float ov = __shfl_xor(m, off, 64);
            int   oi = __shfl_xor(mi, off, 64);
            if (ov > m || (ov == m && oi < mi)) { m = ov; mi = oi; }
        }
        // second argmax (top1 removed)
        float v2 = (lane == mi) ? -INFINITY : v;
        float m2 = v2; int mi2 = lane;
        #pragma unroll
        for (int off = 32; off; off >>= 1) {
            float ov = __shfl_xor(m2, off, 64);
            int   oi = __shfl_xor(mi2, off, 64);
            if (ov > m2 || (ov == m2 && oi < mi2)) { m2 = ov; mi2 = oi; }
        }
        // softmax denom
        float ex = expf(v - m);
        float s = ex;
        #pragma unroll
        for (int off = 32; off; off >>= 1) s += __shfl_xor(s, off, 64);

        float inv   = 1.0f / s;
        float gate1 = inv;                 // exp(0)/s
        float gate2 = expf(m2 - m) * inv;
        gsum_acc += ex * inv;              // raw gate for (token t, expert lane)

        float denom = gate1 + gate2 + 1e-9f;
        float g1n = gate1 / denom;
        float g2n = gate2 / denom;

        int gt = tok0 + t;
        if (lane == 0) {
            float u = noise[gt];
            idx1[gt]  = mi;
            idx2[gt]  = mi2;
            g1o[gt]   = g1n;
            g2o[gt]   = g2n;
            keep2[gt] = (u < (g2n / 0.2f)) ? 1 : 0;
        }
    }

    sG[wv][lane] = gsum_acc;
    __syncthreads();
    if (tid < 64) {
        float tot = sG[0][tid] + sG[1][tid] + sG[2][tid] + sG[3][tid];
        atomicAdd(&sumG[b * NEXP + tid], tot);
    }
}

// K2: per-(batch, expert) sequential position scan. One block/batch,
// thread == expert. pos2 recorded WITHOUT the mask_1_count base (added at
// scatter) so one pass suffices.
__global__ __launch_bounds__(64) void k_pos(
    const int* __restrict__ idx1, const int* __restrict__ idx2,
    const int* __restrict__ keep2,
    int* __restrict__ pos1, int* __restrict__ pos2raw,
    int* __restrict__ cnt1tot)
{
    const int b = blockIdx.x;
    const int e = threadIdx.x;
    __shared__ int s1[64], s2[64], sk[64];
    int c1 = 0, c2 = 0;
    const int base = b * NPB;
    for (int c0 = 0; c0 < NPB; c0 += 64) {
        s1[e] = idx1[base + c0 + e];
        s2[e] = idx2[base + c0 + e];
        sk[e] = keep2[base + c0 + e];
        __syncthreads();
        #pragma unroll 8
        for (int j = 0; j < 64; ++j) {
            if (s1[j] == e) { pos1[base + c0 + j] = c1; c1++; }
            if (sk[j] && s2[j] == e) { pos2raw[base + c0 + j] = c2; c2++; }
        }
        __syncthreads();
    }
    cnt1tot[b * NEXP + e] = c1;   // pre-capacity total (density_1 uses this)
}

// K3: sparse scatter of the <=2 nonzeros per token into combine/dispatch.
__global__ __launch_bounds__(256) void k_scat(
    const int* __restrict__ idx1, const int* __restrict__ idx2,
    const int* __restrict__ keep2,
    const int* __restrict__ pos1, const int* __restrict__ pos2raw,
    const int* __restrict__ cnt1tot,
    const float* __restrict__ g1, const float* __restrict__ g2,
    float* __restrict__ out)
{
    int t = blockIdx.x * 256 + threadIdx.x;
    if (t >= NTOK) return;
    int b = t >> 11;
    float* dispatch = out;
    float* combine  = out + (size_t)SOUT;

    int p1 = pos1[t];
    if (p1 < CAP) {
        int i1 = idx1[t];
        size_t off = ((size_t)t * NEXP + i1) * CAP + p1;
        combine[off]  = g1[t];
        dispatch[off] = 1.0f;
    }
    if (keep2[t]) {
        int i2  = idx2[t];
        int m1c = min(cnt1tot[b * NEXP + i2], CAP);
        int p2  = pos2raw[t] + m1c;
        if (p2 < CAP) {
            size_t off = ((size_t)t * NEXP + i2) * CAP + p2;
            combine[off]  = g2[t];
            dispatch[off] = 1.0f;
        }
    }
}

// K4: loss = sum_{b,e} sumG * cnt / (b*n^2/e) = sum / 524288
__global__ __launch_bounds__(512) void k_loss(
    const float* __restrict__ sumG, const int* __restrict__ cnt1tot,
    float* __restrict__ out)
{
    __shared__ float red[8];
    int tid = threadIdx.x;   // 512 = b*e
    float v = sumG[tid] * (float)cnt1tot[tid];
    #pragma unroll
    for (int off = 32; off; off >>= 1) v += __shfl_xor(v, off, 64);
    if ((tid & 63) == 0) red[tid >> 6] = v;
    __syncthreads();
    if (tid == 0) {
        float s = 0.f;
        #pragma unroll
        for (int i = 0; i < 8; ++i) s += red[i];
        out[2 * SOUT] = s * (1.0f / 524288.0f);
    }
}

extern "C" void kernel_launch(void* const* d_in, const int* in_sizes, int n_in,
                              void* d_out, int out_size, void* d_ws, size_t ws_size,
                              hipStream_t stream) {
    (void)in_sizes; (void)n_in; (void)ws_size;
    const float* x     = (const float*)d_in[0];
    const float* w     = (const float*)d_in[1];
    const float* noise = (const float*)d_in[2];
    float* out = (float*)d_out;
    char*  ws  = (char*)d_ws;

    int*   idx1    = (int*)  (ws + OFF_IDX1);
    int*   idx2    = (int*)  (ws + OFF_IDX2);
    int*   keep2   = (int*)  (ws + OFF_KEEP2);
    int*   pos1    = (int*)  (ws + OFF_POS1);
    int*   pos2raw = (int*)  (ws + OFF_POS2);
    float* g1      = (float*)(ws + OFF_G1);
    float* g2      = (float*)(ws + OFF_G2);
    float* sumG    = (float*)(ws + OFF_SUMG);
    int*   cnt1tot = (int*)  (ws + OFF_CNT1);

    // zero the (mostly-zero) 671 MB output and the atomic accumulators
    hipMemsetAsync(d_out, 0, (size_t)out_size * sizeof(float), stream);
    hipMemsetAsync(ws + OFF_SUMG, 0, 512 * sizeof(float), stream);

    k_gate<<<dim3(NTOK / 64), dim3(256), 0, stream>>>(
        x, w, noise, idx1, idx2, keep2, g1, g2, sumG);
    k_pos<<<dim3(8), dim3(64), 0, stream>>>(
        idx1, idx2, keep2, pos1, pos2raw, cnt1tot);
    k_scat<<<dim3(NTOK / 256), dim3(256), 0, stream>>>(
        idx1, idx2, keep2, pos1, pos2raw, cnt1tot, g1, g2, out);
    k_loss<<<dim3(1), dim3(512), 0, stream>>>(sumG, cnt1tot, out);
}

// Round 2
// 976.956 us; speedup vs baseline: 1.0166x; 1.0166x over previous
//
#include <hip/hip_runtime.h>
#include <math.h>

#define NTOK 16384      // b*n = 8*2048
#define NPB  2048       // tokens per batch
#define DDIM 1024
#define NEXP 64
#define CAP  80
#define SOUT 83886080LL // NTOK*NEXP*CAP

// workspace layout (bytes)
#define OFF_ROUTE  0                      // NTOK int (idx1 | idx2<<8 | keep2<<16)
#define OFF_POS1   (OFF_ROUTE + NTOK*4)   // NTOK int
#define OFF_POS2   (OFF_POS1  + NTOK*4)   // NTOK int
#define OFF_CNT1   (OFF_POS2  + NTOK*4)   // 512 int (pre-capacity top1 counts)
#define OFF_PART   (OFF_CNT1  + 2048)     // 256*64 float (per-block raw-gate sums)
#define OFF_G12    (OFF_PART  + 65536)    // NTOK float2

// K0: zero the 2*SOUT output elements (loss slot written by loss path).
__global__ __launch_bounds__(256) void k_zero(float4* __restrict__ out4) {
    const size_t n4 = (2 * SOUT) / 4;
    size_t i = (size_t)blockIdx.x * 256 + threadIdx.x;
    const size_t stride = (size_t)gridDim.x * 256;
    const float4 z = {0.f, 0.f, 0.f, 0.f};
    for (; i < n4; i += stride) out4[i] = z;
}

// K1: fused logits GEMM (64 tokens x 64 experts per block, K=1024) +
// softmax + top1/top2 + renorm + keep2 + per-block raw-gate sums for loss.
__global__ __launch_bounds__(256) void k_gate(
    const float* __restrict__ x, const float* __restrict__ w,
    const float* __restrict__ noise,
    int* __restrict__ route, float2* __restrict__ g12,
    float* __restrict__ part)
{
    __shared__ float xs[32][68];   // x tile, transposed: xs[k][token]
    __shared__ float wl[32][64];   // w tile: wl[k][expert]
    __shared__ float lg[64][65];   // logits tile
    __shared__ float sG[4][64];    // per-wave raw-gate sums

    const int tid  = threadIdx.x;
    const int tok0 = blockIdx.x * 64;
    const int tx = tid & 15, ty = tid >> 4;   // expert quad / token quad
    float acc[4][4] = {{0.f}};

    const float* xb = x + (size_t)tok0 * DDIM;

    for (int k0 = 0; k0 < DDIM; k0 += 32) {
        #pragma unroll
        for (int r = 0; r < 2; ++r) {
            int f = tid + r * 256;            // 0..511 (float4 slots)
            int t = f >> 3, c = f & 7;
            float4 v = *(const float4*)(xb + (size_t)t * DDIM + k0 + 4 * c);
            xs[4*c+0][t] = v.x; xs[4*c+1][t] = v.y;
            xs[4*c+2][t] = v.z; xs[4*c+3][t] = v.w;
            ((float4*)wl)[f] = ((const float4*)(w + (size_t)k0 * NEXP))[f];
        }
        __syncthreads();
        #pragma unroll
        for (int k = 0; k < 32; ++k) {
            float4 a  = *(const float4*)&xs[k][ty * 4];
            float4 bb = *(const float4*)&wl[k][tx * 4];
            float av[4] = {a.x, a.y, a.z, a.w};
            float bv[4] = {bb.x, bb.y, bb.z, bb.w};
            #pragma unroll
            for (int i = 0; i < 4; ++i)
                #pragma unroll
                for (int j = 0; j < 4; ++j)
                    acc[i][j] = fmaf(av[i], bv[j], acc[i][j]);
        }
        __syncthreads();
    }

    #pragma unroll
    for (int i = 0; i < 4; ++i)
        #pragma unroll
        for (int j = 0; j < 4; ++j)
            lg[ty * 4 + i][tx * 4 + j] = acc[i][j];
    __syncthreads();

    // softmax + top2 per token: lane == expert, wave handles 16 tokens
    const int lane = tid & 63;
    const int wv   = tid >> 6;
    float gsum_acc = 0.f;

    for (int it = 0; it < 16; ++it) {
        int t = wv * 16 + it;
        float v = lg[t][lane];

        float m = v; int mi = lane;
        #pragma unroll
        for (int off = 32; off; off >>= 1) {
            float ov = __shfl_xor(m, off, 64);
            int   oi = __shfl_xor(mi, off, 64);
            if (ov > m || (ov == m && oi < mi)) { m = ov; mi = oi; }
        }
        float v2 = (lane == mi) ? -INFINITY : v;
        float m2 = v2; int mi2 = lane;
        #pragma unroll
        for (int off = 32; off; off >>= 1) {
            float ov = __shfl_xor(m2, off, 64);
            int   oi = __shfl_xor(mi2, off, 64);
            if (ov > m2 || (ov == m2 && oi < mi2)) { m2 = ov; mi2 = oi; }
        }
        float ex = expf(v - m);
        float s = ex;
        #pragma unroll
        for (int off = 32; off; off >>= 1) s += __shfl_xor(s, off, 64);

        float inv   = 1.0f / s;
        float gate1 = inv;
        float gate2 = expf(m2 - m) * inv;
        gsum_acc += ex * inv;

        float denom = gate1 + gate2 + 1e-9f;
        float g1n = gate1 / denom;
        float g2n = gate2 / denom;

        int gt = tok0 + t;
        if (lane == 0) {
            float u = noise[gt];
            int k2 = (u < (g2n / 0.2f)) ? 1 : 0;
            route[gt] = mi | (mi2 << 8) | (k2 << 16);
            g12[gt] = make_float2(g1n, g2n);
        }
    }

    sG[wv][lane] = gsum_acc;
    __syncthreads();
    if (tid < 64)
        part[blockIdx.x * 64 + tid] =
            sG[0][tid] + sG[1][tid] + sG[2][tid] + sG[3][tid];
}

// K2: per-(batch, expert) sequential position scan. One block/batch,
// thread == expert. pos2 recorded WITHOUT the mask_1_count base.
__global__ __launch_bounds__(64) void k_pos(
    const int* __restrict__ route,
    int* __restrict__ pos1, int* __restrict__ pos2raw,
    int* __restrict__ cnt1tot)
{
    const int b = blockIdx.x;
    const int e = threadIdx.x;
    __shared__ int sr[64];
    int c1 = 0, c2 = 0;
    const int base = b * NPB;
    for (int c0 = 0; c0 < NPB; c0 += 64) {
        sr[e] = route[base + c0 + e];
        __syncthreads();
        #pragma unroll 8
        for (int j = 0; j < 64; ++j) {
            int r = sr[j];
            if ((r & 255) == e) { pos1[base + c0 + j] = c1; c1++; }
            if ((r >> 16) && ((r >> 8) & 255) == e) { pos2raw[base + c0 + j] = c2; c2++; }
        }
        __syncthreads();
    }
    cnt1tot[b * NEXP + e] = c1;   // pre-capacity total (density_1 uses this)
}

// K3: sparse scatter of <=2 nonzeros per token; block 64 computes the loss.
__global__ __launch_bounds__(256) void k_scat(
    const int* __restrict__ route,
    const int* __restrict__ pos1, const int* __restrict__ pos2raw,
    const int* __restrict__ cnt1tot,
    const float2* __restrict__ g12, const float* __restrict__ part,
    float* __restrict__ out)
{
    const int tid = threadIdx.x;
    if (blockIdx.x == 64) {
        // loss = sum_{b,e} sumG[b,e] * cnt1tot[b,e] / 524288
        __shared__ float red[4];
        float v = 0.f;
        for (int p = tid; p < 512; p += 256) {
            int b = p >> 6, e = p & 63;
            float s = 0.f;
            #pragma unroll 8
            for (int c = 0; c < 32; ++c) s += part[(b * 32 + c) * 64 + e];
            v += s * (float)cnt1tot[p];
        }
        #pragma unroll
        for (int off = 32; off; off >>= 1) v += __shfl_xor(v, off, 64);
        if ((tid & 63) == 0) red[tid >> 6] = v;
        __syncthreads();
        if (tid == 0)
            out[2 * SOUT] = (red[0] + red[1] + red[2] + red[3]) * (1.0f / 524288.0f);
        return;
    }

    int t = blockIdx.x * 256 + tid;
    int b = t >> 11;
    float* dispatch = out;
    float* combine  = out + (size_t)SOUT;

    int r  = route[t];
    int i1 = r & 255, i2 = (r >> 8) & 255, k2 = (r >> 16);
    float2 g = g12[t];

    int p1 = pos1[t];
    if (p1 < CAP) {
        size_t off = ((size_t)t * NEXP + i1) * CAP + p1;
        combine[off]  = g.x;
        dispatch[off] = 1.0f;
    }
    if (k2) {
        int m1c = min(cnt1tot[b * NEXP + i2], CAP);
        int p2  = pos2raw[t] + m1c;
        if (p2 < CAP) {
            size_t off = ((size_t)t * NEXP + i2) * CAP + p2;
            combine[off]  = g.y;
            dispatch[off] = 1.0f;
        }
    }
}

extern "C" void kernel_launch(void* const* d_in, const int* in_sizes, int n_in,
                              void* d_out, int out_size, void* d_ws, size_t ws_size,
                              hipStream_t stream) {
    (void)in_sizes; (void)n_in; (void)ws_size; (void)out_size;
    const float* x     = (const float*)d_in[0];
    const float* w     = (const float*)d_in[1];
    const float* noise = (const float*)d_in[2];
    float* out = (float*)d_out;
    char*  ws  = (char*)d_ws;

    int*    route   = (int*)   (ws + OFF_ROUTE);
    int*    pos1    = (int*)   (ws + OFF_POS1);
    int*    pos2raw = (int*)   (ws + OFF_POS2);
    int*    cnt1tot = (int*)   (ws + OFF_CNT1);
    float*  part    = (float*) (ws + OFF_PART);
    float2* g12     = (float2*)(ws + OFF_G12);

    k_gate<<<dim3(NTOK / 64), dim3(256), 0, stream>>>(
        x, w, noise, route, g12, part);
    k_zero<<<dim3(4096), dim3(256), 0, stream>>>((float4*)out);
    k_pos<<<dim3(8), dim3(64), 0, stream>>>(
        route, pos1, pos2raw, cnt1tot);
    k_scat<<<dim3(65), dim3(256), 0, stream>>>(
        route, pos1, pos2raw, cnt1tot, g12, part, out);
}

// Round 3
// 913.373 us; speedup vs baseline: 1.0873x; 1.0696x over previous
//
#include <hip/hip_runtime.h>
#include <math.h>

#define NTOK 16384      // b*n = 8*2048
#define NPB  2048       // tokens per batch
#define DDIM 1024
#define NEXP 64
#define CAP  80
#define ROWF 5120       // NEXP*CAP floats per token row
#define SOUT 83886080LL // NTOK*NEXP*CAP

// workspace layout (bytes)
#define OFF_ROUTE  0                        // NTOK int (idx1 | idx2<<8 | keep2<<16)
#define OFF_POS1   (OFF_ROUTE + NTOK*4)     // NTOK int
#define OFF_POS2   (OFF_POS1  + NTOK*4)     // NTOK int
#define OFF_CNT1   (OFF_POS2  + NTOK*4)     // 512 int
#define OFF_PART   (OFF_CNT1  + 2048)       // 512*64 float per-block raw-gate sums
#define OFF_G12    (OFF_PART  + 131072)     // NTOK float2

// K1: fused logits GEMM (32 tokens x 64 experts per block, K=1024) +
// softmax + top1/top2 + renorm + keep2 + per-block raw-gate sums.
// 512 blocks -> 2 blocks/CU -> 2 waves/SIMD for latency hiding.
__global__ __launch_bounds__(256) void k_gate(
    const float* __restrict__ x, const float* __restrict__ w,
    const float* __restrict__ noise,
    int* __restrict__ route, float2* __restrict__ g12,
    float* __restrict__ part)
{
    __shared__ float xs[32][34];   // xs[k][token], pad 34 keeps float2 align + 2-way banks
    __shared__ float wl[32][64];   // wl[k][expert]
    __shared__ float lg[32][68];   // logits tile
    __shared__ float sG[4][64];    // per-wave raw-gate sums

    const int tid  = threadIdx.x;
    const int tok0 = blockIdx.x * 32;
    const int tx = tid & 15, ty = tid >> 4;   // expert quad / token pair
    float acc[2][4] = {{0.f}};

    const float* xb = x + (size_t)tok0 * DDIM;

    for (int k0 = 0; k0 < DDIM; k0 += 32) {
        {
            int t = tid >> 3, c = tid & 7;    // token 0..31, float4 col 0..7
            float4 v = *(const float4*)(xb + (size_t)t * DDIM + k0 + 4 * c);
            xs[4*c+0][t] = v.x; xs[4*c+1][t] = v.y;
            xs[4*c+2][t] = v.z; xs[4*c+3][t] = v.w;
            const float4* wp = (const float4*)(w + (size_t)k0 * NEXP);
            ((float4*)wl)[tid]       = wp[tid];
            ((float4*)wl)[tid + 256] = wp[tid + 256];
        }
        __syncthreads();
        #pragma unroll
        for (int k = 0; k < 32; ++k) {
            float2 a  = *(const float2*)&xs[k][ty * 2];
            float4 bb = *(const float4*)&wl[k][tx * 4];
            float av[2] = {a.x, a.y};
            float bv[4] = {bb.x, bb.y, bb.z, bb.w};
            #pragma unroll
            for (int i = 0; i < 2; ++i)
                #pragma unroll
                for (int j = 0; j < 4; ++j)
                    acc[i][j] = fmaf(av[i], bv[j], acc[i][j]);
        }
        __syncthreads();
    }

    #pragma unroll
    for (int i = 0; i < 2; ++i)
        #pragma unroll
        for (int j = 0; j < 4; ++j)
            lg[ty * 2 + i][tx * 4 + j] = acc[i][j];
    __syncthreads();

    // softmax + top2: lane == expert, wave handles 8 tokens
    const int lane = tid & 63;
    const int wv   = tid >> 6;
    float gsum_acc = 0.f;

    for (int it = 0; it < 8; ++it) {
        int t = wv * 8 + it;
        float v = lg[t][lane];

        float m = v; int mi = lane;
        #pragma unroll
        for (int off = 32; off; off >>= 1) {
            float ov = __shfl_xor(m, off, 64);
            int   oi = __shfl_xor(mi, off, 64);
            if (ov > m || (ov == m && oi < mi)) { m = ov; mi = oi; }
        }
        float v2 = (lane == mi) ? -INFINITY : v;
        float m2 = v2; int mi2 = lane;
        #pragma unroll
        for (int off = 32; off; off >>= 1) {
            float ov = __shfl_xor(m2, off, 64);
            int   oi = __shfl_xor(mi2, off, 64);
            if (ov > m2 || (ov == m2 && oi < mi2)) { m2 = ov; mi2 = oi; }
        }
        float ex = expf(v - m);
        float s = ex;
        #pragma unroll
        for (int off = 32; off; off >>= 1) s += __shfl_xor(s, off, 64);

        float inv   = 1.0f / s;
        float gate1 = inv;
        float gate2 = expf(m2 - m) * inv;
        gsum_acc += ex * inv;

        float denom = gate1 + gate2 + 1e-9f;
        float g1n = gate1 / denom;
        float g2n = gate2 / denom;

        int gt = tok0 + t;
        if (lane == 0) {
            float u = noise[gt];
            int k2 = (u < (g2n / 0.2f)) ? 1 : 0;
            route[gt] = mi | (mi2 << 8) | (k2 << 16);
            g12[gt] = make_float2(g1n, g2n);
        }
    }

    sG[wv][lane] = gsum_acc;
    __syncthreads();
    if (tid < 64)
        part[blockIdx.x * 64 + tid] =
            sG[0][tid] + sG[1][tid] + sG[2][tid] + sG[3][tid];
}

// K2: per-(batch, expert) sequential position scan (pos2 without mask_1_count).
__global__ __launch_bounds__(64) void k_pos(
    const int* __restrict__ route,
    int* __restrict__ pos1, int* __restrict__ pos2raw,
    int* __restrict__ cnt1tot)
{
    const int b = blockIdx.x;
    const int e = threadIdx.x;
    __shared__ int sr[64];
    int c1 = 0, c2 = 0;
    const int base = b * NPB;
    for (int c0 = 0; c0 < NPB; c0 += 64) {
        sr[e] = route[base + c0 + e];
        __syncthreads();
        #pragma unroll 8
        for (int j = 0; j < 64; ++j) {
            int r = sr[j];
            if ((r & 255) == e) { pos1[base + c0 + j] = c1; c1++; }
            if ((r >> 16) && ((r >> 8) & 255) == e) { pos2raw[base + c0 + j] = c2; c2++; }
        }
        __syncthreads();
    }
    cnt1tot[b * NEXP + e] = c1;
}

// K3: write the WHOLE output (zeros + inserted gate values) in one streaming
// pass. Block bid<4096: dispatch rows of tokens bid*4..+3; bid in [4096,8192):
// combine rows; bid==8192: loss.
__global__ __launch_bounds__(256) void k_out(
    const int* __restrict__ route,
    const int* __restrict__ pos1, const int* __restrict__ pos2raw,
    const int* __restrict__ cnt1tot,
    const float2* __restrict__ g12, const float* __restrict__ part,
    float* __restrict__ out)
{
    const int tid = threadIdx.x;
    const int bid = blockIdx.x;

    if (bid == 8192) {
        // loss = sum_{b,e} rawGateSum[b,e] * cnt1tot[b,e] / 524288
        __shared__ float red[4];
        float v = 0.f;
        for (int p = tid; p < 512; p += 256) {
            int b = p >> 6, e = p & 63;
            float s = 0.f;
            for (int c = 0; c < 64; ++c) s += part[((b << 6) + c) * 64 + e];
            v += s * (float)cnt1tot[p];
        }
        #pragma unroll
        for (int off = 32; off; off >>= 1) v += __shfl_xor(v, off, 64);
        if ((tid & 63) == 0) red[tid >> 6] = v;
        __syncthreads();
        if (tid == 0)
            out[2 * SOUT] = (red[0] + red[1] + red[2] + red[3]) * (1.0f / 524288.0f);
        return;
    }

    const int half = bid >> 12;           // 0: dispatch, 1: combine
    const int tg   = (bid & 4095) * 4;    // first token of this block's group

    __shared__ int   se[4][2];            // flat in-row position (0..5119) or -1
    __shared__ float sv[4][2];            // value to insert

    if (tid < 4) {
        int t = tg + tid;
        int b = t >> 11;
        int r  = route[t];
        int i1 = r & 255, i2 = (r >> 8) & 255, k2 = (r >> 16);
        float2 g = g12[t];

        int p1 = pos1[t];
        se[tid][0] = (p1 < CAP) ? (i1 * CAP + p1) : -1;
        sv[tid][0] = half ? g.x : 1.0f;

        int e2 = -1;
        if (k2) {
            int m1c = min(cnt1tot[(b << 6) + i2], CAP);
            int p2  = pos2raw[t] + m1c;
            if (p2 < CAP) e2 = i2 * CAP + p2;
        }
        se[tid][1] = e2;
        sv[tid][1] = half ? g.y : 1.0f;
    }
    __syncthreads();

    float* base = out + (half ? (size_t)SOUT : 0) + (size_t)tg * ROWF;
    #pragma unroll
    for (int t = 0; t < 4; ++t) {
        const int   e1 = se[t][0], e2 = se[t][1];
        const float v1 = sv[t][0], v2 = sv[t][1];
        float4* p = (float4*)(base + (size_t)t * ROWF);
        for (int s = tid; s < ROWF / 4; s += 256) {
            int b4 = s * 4;
            float4 v;
            v.x = (b4     == e1) ? v1 : ((b4     == e2) ? v2 : 0.f);
            v.y = (b4 + 1 == e1) ? v1 : ((b4 + 1 == e2) ? v2 : 0.f);
            v.z = (b4 + 2 == e1) ? v1 : ((b4 + 2 == e2) ? v2 : 0.f);
            v.w = (b4 + 3 == e1) ? v1 : ((b4 + 3 == e2) ? v2 : 0.f);
            p[s] = v;
        }
    }
}

extern "C" void kernel_launch(void* const* d_in, const int* in_sizes, int n_in,
                              void* d_out, int out_size, void* d_ws, size_t ws_size,
                              hipStream_t stream) {
    (void)in_sizes; (void)n_in; (void)ws_size; (void)out_size;
    const float* x     = (const float*)d_in[0];
    const float* w     = (const float*)d_in[1];
    const float* noise = (const float*)d_in[2];
    float* out = (float*)d_out;
    char*  ws  = (char*)d_ws;

    int*    route   = (int*)   (ws + OFF_ROUTE);
    int*    pos1    = (int*)   (ws + OFF_POS1);
    int*    pos2raw = (int*)   (ws + OFF_POS2);
    int*    cnt1tot = (int*)   (ws + OFF_CNT1);
    float*  part    = (float*) (ws + OFF_PART);
    float2* g12     = (float2*)(ws + OFF_G12);

    k_gate<<<dim3(NTOK / 32), dim3(256), 0, stream>>>(
        x, w, noise, route, g12, part);
    k_pos<<<dim3(8), dim3(64), 0, stream>>>(
        route, pos1, pos2raw, cnt1tot);
    k_out<<<dim3(8193), dim3(256), 0, stream>>>(
        route, pos1, pos2raw, cnt1tot, g12, part, out);
}

// Round 5
// 903.075 us; speedup vs baseline: 1.0997x; 1.0114x over previous
//
#include <hip/hip_runtime.h>
#include <math.h>

#define NTOK 16384      // b*n = 8*2048
#define NPB  2048       // tokens per batch
#define DDIM 1024
#define NEXP 64
#define CAP  80
#define ROWF 5120       // NEXP*CAP floats per token row
#define SOUT 83886080LL // NTOK*NEXP*CAP

typedef float vf4 __attribute__((ext_vector_type(4)));  // nontemporal-store-able

// workspace layout (bytes)
#define OFF_ROUTE  0                        // NTOK int (idx1 | idx2<<8 | keep2<<16)
#define OFF_POS1   (OFF_ROUTE + NTOK*4)     // NTOK int
#define OFF_POS2   (OFF_POS1  + NTOK*4)     // NTOK int
#define OFF_CNT1   (OFF_POS2  + NTOK*4)     // 512 int
#define OFF_PART   (OFF_CNT1  + 2048)       // 512*64 float per-block raw-gate sums
#define OFF_G12    (OFF_PART  + 131072)     // NTOK float2

// K1: fused logits GEMM (32 tokens x 64 experts per block, K=1024) +
// softmax + top1/top2 + renorm + keep2 + per-block raw-gate sums.
__global__ __launch_bounds__(256) void k_gate(
    const float* __restrict__ x, const float* __restrict__ w,
    const float* __restrict__ noise,
    int* __restrict__ route, float2* __restrict__ g12,
    float* __restrict__ part)
{
    __shared__ float xs[32][34];   // xs[k][token]
    __shared__ float wl[32][64];   // wl[k][expert]
    __shared__ float lg[32][68];   // logits tile
    __shared__ float sG[4][64];    // per-wave raw-gate sums

    const int tid  = threadIdx.x;
    const int tok0 = blockIdx.x * 32;
    const int tx = tid & 15, ty = tid >> 4;   // expert quad / token pair
    float acc[2][4] = {{0.f}};

    const float* xb = x + (size_t)tok0 * DDIM;

    for (int k0 = 0; k0 < DDIM; k0 += 32) {
        {
            int t = tid >> 3, c = tid & 7;
            float4 v = *(const float4*)(xb + (size_t)t * DDIM + k0 + 4 * c);
            xs[4*c+0][t] = v.x; xs[4*c+1][t] = v.y;
            xs[4*c+2][t] = v.z; xs[4*c+3][t] = v.w;
            const float4* wp = (const float4*)(w + (size_t)k0 * NEXP);
            ((float4*)wl)[tid]       = wp[tid];
            ((float4*)wl)[tid + 256] = wp[tid + 256];
        }
        __syncthreads();
        #pragma unroll
        for (int k = 0; k < 32; ++k) {
            float2 a  = *(const float2*)&xs[k][ty * 2];
            float4 bb = *(const float4*)&wl[k][tx * 4];
            float av[2] = {a.x, a.y};
            float bv[4] = {bb.x, bb.y, bb.z, bb.w};
            #pragma unroll
            for (int i = 0; i < 2; ++i)
                #pragma unroll
                for (int j = 0; j < 4; ++j)
                    acc[i][j] = fmaf(av[i], bv[j], acc[i][j]);
        }
        __syncthreads();
    }

    #pragma unroll
    for (int i = 0; i < 2; ++i)
        #pragma unroll
        for (int j = 0; j < 4; ++j)
            lg[ty * 2 + i][tx * 4 + j] = acc[i][j];
    __syncthreads();

    const int lane = tid & 63;
    const int wv   = tid >> 6;
    float gsum_acc = 0.f;

    for (int it = 0; it < 8; ++it) {
        int t = wv * 8 + it;
        float v = lg[t][lane];

        float m = v; int mi = lane;
        #pragma unroll
        for (int off = 32; off; off >>= 1) {
            float ov = __shfl_xor(m, off, 64);
            int   oi = __shfl_xor(mi, off, 64);
            if (ov > m || (ov == m && oi < mi)) { m = ov; mi = oi; }
        }
        float v2 = (lane == mi) ? -INFINITY : v;
        float m2 = v2; int mi2 = lane;
        #pragma unroll
        for (int off = 32; off; off >>= 1) {
            float ov = __shfl_xor(m2, off, 64);
            int   oi = __shfl_xor(mi2, off, 64);
            if (ov > m2 || (ov == m2 && oi < mi2)) { m2 = ov; mi2 = oi; }
        }
        float ex = expf(v - m);
        float s = ex;
        #pragma unroll
        for (int off = 32; off; off >>= 1) s += __shfl_xor(s, off, 64);

        float inv   = 1.0f / s;
        float gate1 = inv;
        float gate2 = expf(m2 - m) * inv;
        gsum_acc += ex * inv;

        float denom = gate1 + gate2 + 1e-9f;
        float g1n = gate1 / denom;
        float g2n = gate2 / denom;

        int gt = tok0 + t;
        if (lane == 0) {
            float u = noise[gt];
            int k2 = (u < (g2n / 0.2f)) ? 1 : 0;
            route[gt] = mi | (mi2 << 8) | (k2 << 16);
            g12[gt] = make_float2(g1n, g2n);
        }
    }

    sG[wv][lane] = gsum_acc;
    __syncthreads();
    if (tid < 64)
        part[blockIdx.x * 64 + tid] =
            sG[0][tid] + sG[1][tid] + sG[2][tid] + sG[3][tid];
}

// K2: per-(batch, expert) sequential position scan, with register prefetch
// of the next 64-token tile to hide global-load latency.
__global__ __launch_bounds__(64) void k_pos(
    const int* __restrict__ route,
    int* __restrict__ pos1, int* __restrict__ pos2raw,
    int* __restrict__ cnt1tot)
{
    const int b = blockIdx.x;
    const int e = threadIdx.x;
    __shared__ int sr[64];
    int c1 = 0, c2 = 0;
    const int base = b * NPB;
    int nxt = route[base + e];
    for (int c0 = 0; c0 < NPB; c0 += 64) {
        sr[e] = nxt;
        __syncthreads();
        if (c0 + 64 < NPB) nxt = route[base + c0 + 64 + e];  // prefetch
        #pragma unroll 8
        for (int j = 0; j < 64; ++j) {
            int r = sr[j];
            if ((r & 255) == e) { pos1[base + c0 + j] = c1; c1++; }
            if ((r >> 16) && ((r >> 8) & 255) == e) { pos2raw[base + c0 + j] = c2; c2++; }
        }
        __syncthreads();
    }
    cnt1tot[b * NEXP + e] = c1;
}

// K3: single streaming pass writes BOTH halves (dispatch + combine) for 4
// tokens per block, nontemporal stores; block 4096 computes the loss.
__global__ __launch_bounds__(256) void k_out(
    const int* __restrict__ route,
    const int* __restrict__ pos1, const int* __restrict__ pos2raw,
    const int* __restrict__ cnt1tot,
    const float2* __restrict__ g12, const float* __restrict__ part,
    float* __restrict__ out)
{
    const int tid = threadIdx.x;
    const int bid = blockIdx.x;

    if (bid == 4096) {
        __shared__ float red[4];
        float v = 0.f;
        for (int p = tid; p < 512; p += 256) {
            int b = p >> 6, e = p & 63;
            float s = 0.f;
            for (int c = 0; c < 64; ++c) s += part[((b << 6) + c) * 64 + e];
            v += s * (float)cnt1tot[p];
        }
        #pragma unroll
        for (int off = 32; off; off >>= 1) v += __shfl_xor(v, off, 64);
        if ((tid & 63) == 0) red[tid >> 6] = v;
        __syncthreads();
        if (tid == 0)
            out[2 * SOUT] = (red[0] + red[1] + red[2] + red[3]) * (1.0f / 524288.0f);
        return;
    }

    const int tg = bid * 4;               // first token of this block's group

    __shared__ int   se[4][2];            // flat in-row position (0..5119) or -1
    __shared__ float sv[4][2];            // combine values

    if (tid < 4) {
        int t = tg + tid;
        int b = t >> 11;
        int r  = route[t];
        int i1 = r & 255, i2 = (r >> 8) & 255, k2 = (r >> 16);
        float2 g = g12[t];

        int p1 = pos1[t];
        se[tid][0] = (p1 < CAP) ? (i1 * CAP + p1) : -1;
        sv[tid][0] = g.x;

        int e2 = -1;
        if (k2) {
            int m1c = min(cnt1tot[(b << 6) + i2], CAP);
            int p2  = pos2raw[t] + m1c;
            if (p2 < CAP) e2 = i2 * CAP + p2;
        }
        se[tid][1] = e2;
        sv[tid][1] = g.y;
    }
    __syncthreads();

    vf4* dbase = (vf4*)(out + (size_t)tg * ROWF);
    vf4* cbase = (vf4*)(out + (size_t)SOUT + (size_t)tg * ROWF);
    #pragma unroll
    for (int t = 0; t < 4; ++t) {
        const int   e1 = se[t][0], e2 = se[t][1];
        const float v1 = sv[t][0], v2 = sv[t][1];
        vf4* pd = dbase + (size_t)t * (ROWF / 4);
        vf4* pc = cbase + (size_t)t * (ROWF / 4);
        for (int s = tid; s < ROWF / 4; s += 256) {
            int b4 = s * 4;
            bool a0 = (b4     == e1), b0 = (b4     == e2);
            bool a1 = (b4 + 1 == e1), b1 = (b4 + 1 == e2);
            bool a2 = (b4 + 2 == e1), b2 = (b4 + 2 == e2);
            bool a3 = (b4 + 3 == e1), b3 = (b4 + 3 == e2);
            vf4 c, d;
            c.x = a0 ? v1 : (b0 ? v2 : 0.f);  d.x = (a0 | b0) ? 1.f : 0.f;
            c.y = a1 ? v1 : (b1 ? v2 : 0.f);  d.y = (a1 | b1) ? 1.f : 0.f;
            c.z = a2 ? v1 : (b2 ? v2 : 0.f);  d.z = (a2 | b2) ? 1.f : 0.f;
            c.w = a3 ? v1 : (b3 ? v2 : 0.f);  d.w = (a3 | b3) ? 1.f : 0.f;
            __builtin_nontemporal_store(d, pd + s);
            __builtin_nontemporal_store(c, pc + s);
        }
    }
}

extern "C" void kernel_launch(void* const* d_in, const int* in_sizes, int n_in,
                              void* d_out, int out_size, void* d_ws, size_t ws_size,
                              hipStream_t stream) {
    (void)in_sizes; (void)n_in; (void)ws_size; (void)out_size;
    const float* x     = (const float*)d_in[0];
    const float* w     = (const float*)d_in[1];
    const float* noise = (const float*)d_in[2];
    float* out = (float*)d_out;
    char*  ws  = (char*)d_ws;

    int*    route   = (int*)   (ws + OFF_ROUTE);
    int*    pos1    = (int*)   (ws + OFF_POS1);
    int*    pos2raw = (int*)   (ws + OFF_POS2);
    int*    cnt1tot = (int*)   (ws + OFF_CNT1);
    float*  part    = (float*) (ws + OFF_PART);
    float2* g12     = (float2*)(ws + OFF_G12);

    k_gate<<<dim3(NTOK / 32), dim3(256), 0, stream>>>(
        x, w, noise, route, g12, part);
    k_pos<<<dim3(8), dim3(64), 0, stream>>>(
        route, pos1, pos2raw, cnt1tot);
    k_out<<<dim3(4097), dim3(256), 0, stream>>>(
        route, pos1, pos2raw, cnt1tot, g12, part, out);
}

// Round 6
// 800.400 us; speedup vs baseline: 1.2408x; 1.1283x over previous
//
#include <hip/hip_runtime.h>
#include <math.h>

#define NTOK 16384      // b*n = 8*2048
#define NPB  2048       // tokens per batch
#define DDIM 1024
#define NEXP 64
#define CAP  80
#define ROWF 5120       // NEXP*CAP floats per token row
#define SOUT 83886080LL // NTOK*NEXP*CAP

typedef float vf4 __attribute__((ext_vector_type(4)));

// workspace layout (bytes)
#define OFF_ROUTE  0                        // NTOK int (idx1 | idx2<<8 | keep2<<16)
#define OFF_POS1   (OFF_ROUTE + NTOK*4)     // NTOK int
#define OFF_POS2   (OFF_POS1  + NTOK*4)     // NTOK int
#define OFF_CNT1   (OFF_POS2  + NTOK*4)     // 512 int
#define OFF_PART   (OFF_CNT1  + 2048)       // 256*64 float per-block raw-gate sums
#define OFF_G12    (OFF_PART  + 65536)      // NTOK float2

// K1: fused logits GEMM (64 tokens x 64 experts per block, 4x4/thread,
// register-prefetched k-tiles) + softmax + top1/top2 + renorm + keep2 +
// per-block raw-gate sums. LDS inner traffic: 32B per 16 FMA (2 B/FMA).
__global__ __launch_bounds__(256) void k_gate(
    const float* __restrict__ x, const float* __restrict__ w,
    const float* __restrict__ noise,
    int* __restrict__ route, float2* __restrict__ g12,
    float* __restrict__ part)
{
    __shared__ float xs[32][68];   // xs[k][token]
    __shared__ float wl[32][64];   // wl[k][expert]
    __shared__ float lg[64][68];   // logits
    __shared__ float sG[4][64];

    const int tid  = threadIdx.x;
    const int tok0 = blockIdx.x * 64;
    const int tx = tid & 15, ty = tid >> 4;   // expert quad / token quad
    float acc[4][4] = {{0.f}};

    const float* xb = x + (size_t)tok0 * DDIM;
    const int t0 = tid >> 3, c0 = (tid & 7) * 4;   // staging coords

    // preload tile 0 into registers
    float4 px0 = *(const float4*)(xb + (size_t)t0 * DDIM + c0);
    float4 px1 = *(const float4*)(xb + (size_t)(t0 + 32) * DDIM + c0);
    float4 pw0 = ((const float4*)w)[tid];
    float4 pw1 = ((const float4*)w)[tid + 256];

    for (int k0 = 0; k0 < DDIM; k0 += 32) {
        xs[c0+0][t0] = px0.x; xs[c0+1][t0] = px0.y;
        xs[c0+2][t0] = px0.z; xs[c0+3][t0] = px0.w;
        xs[c0+0][t0+32] = px1.x; xs[c0+1][t0+32] = px1.y;
        xs[c0+2][t0+32] = px1.z; xs[c0+3][t0+32] = px1.w;
        ((float4*)wl)[tid]       = pw0;
        ((float4*)wl)[tid + 256] = pw1;
        __syncthreads();

        if (k0 + 32 < DDIM) {   // prefetch next tile while computing this one
            px0 = *(const float4*)(xb + (size_t)t0 * DDIM + k0 + 32 + c0);
            px1 = *(const float4*)(xb + (size_t)(t0 + 32) * DDIM + k0 + 32 + c0);
            const float4* wp = (const float4*)(w + (size_t)(k0 + 32) * NEXP);
            pw0 = wp[tid];
            pw1 = wp[tid + 256];
        }

        #pragma unroll
        for (int k = 0; k < 32; ++k) {
            float4 a  = *(const float4*)&xs[k][ty * 4];
            float4 bb = *(const float4*)&wl[k][tx * 4];
            float av[4] = {a.x, a.y, a.z, a.w};
            float bv[4] = {bb.x, bb.y, bb.z, bb.w};
            #pragma unroll
            for (int i = 0; i < 4; ++i)
                #pragma unroll
                for (int j = 0; j < 4; ++j)
                    acc[i][j] = fmaf(av[i], bv[j], acc[i][j]);
        }
        __syncthreads();
    }

    #pragma unroll
    for (int i = 0; i < 4; ++i)
        *(float4*)&lg[ty * 4 + i][tx * 4] =
            make_float4(acc[i][0], acc[i][1], acc[i][2], acc[i][3]);
    __syncthreads();

    const int lane = tid & 63;
    const int wv   = tid >> 6;
    float gsum_acc = 0.f;

    for (int it = 0; it < 16; ++it) {
        int t = wv * 16 + it;
        float v = lg[t][lane];

        float m = v; int mi = lane;
        #pragma unroll
        for (int off = 32; off; off >>= 1) {
            float ov = __shfl_xor(m, off, 64);
            int   oi = __shfl_xor(mi, off, 64);
            if (ov > m || (ov == m && oi < mi)) { m = ov; mi = oi; }
        }
        float v2 = (lane == mi) ? -INFINITY : v;
        float m2 = v2; int mi2 = lane;
        #pragma unroll
        for (int off = 32; off; off >>= 1) {
            float ov = __shfl_xor(m2, off, 64);
            int   oi = __shfl_xor(mi2, off, 64);
            if (ov > m2 || (ov == m2 && oi < mi2)) { m2 = ov; mi2 = oi; }
        }
        float ex = expf(v - m);
        float s = ex;
        #pragma unroll
        for (int off = 32; off; off >>= 1) s += __shfl_xor(s, off, 64);

        float inv   = 1.0f / s;
        float gate1 = inv;
        float gate2 = expf(m2 - m) * inv;
        gsum_acc += ex * inv;

        float denom = gate1 + gate2 + 1e-9f;
        float g1n = gate1 / denom;
        float g2n = gate2 / denom;

        int gt = tok0 + t;
        if (lane == 0) {
            float u = noise[gt];
            int k2 = (u < (g2n / 0.2f)) ? 1 : 0;
            route[gt] = mi | (mi2 << 8) | (k2 << 16);
            g12[gt] = make_float2(g1n, g2n);
        }
    }

    sG[wv][lane] = gsum_acc;
    __syncthreads();
    if (tid < 64)
        part[blockIdx.x * 64 + tid] =
            sG[0][tid] + sG[1][tid] + sG[2][tid] + sG[3][tid];
}

// K2: 3-phase position scan per batch (one 256-thread block per batch):
// A) per-64-token-tile expert histograms (4 waves x 8 tiles),
// B) exclusive prefix over tiles per expert,
// C) positional rewrite with per-tile bases.
__global__ __launch_bounds__(256) void k_pos(
    const int* __restrict__ route,
    int* __restrict__ pos1, int* __restrict__ pos2raw,
    int* __restrict__ cnt1tot)
{
    const int b    = blockIdx.x;
    const int tid  = threadIdx.x;
    const int lane = tid & 63, wv = tid >> 6;
    __shared__ int sr[NPB];
    __shared__ int h1[32][64], h2[32][64];

    for (int i = tid; i < NPB; i += 256) sr[i] = route[b * NPB + i];
    __syncthreads();

    for (int tau = wv; tau < 32; tau += 4) {
        int c1 = 0, c2 = 0;
        const int* p = &sr[tau * 64];
        #pragma unroll 8
        for (int j = 0; j < 64; ++j) {
            int r = p[j];
            c1 += ((r & 255) == lane);
            c2 += ((r >> 16) && (((r >> 8) & 255) == lane));
        }
        h1[tau][lane] = c1; h2[tau][lane] = c2;
    }
    __syncthreads();

    if (tid < 64) {
        int run = 0;
        #pragma unroll 8
        for (int tau = 0; tau < 32; ++tau) {
            int t = h1[tau][tid]; h1[tau][tid] = run; run += t;
        }
        cnt1tot[b * NEXP + tid] = run;   // pre-capacity top1 total
    } else if (tid < 128) {
        int e = tid - 64, run = 0;
        #pragma unroll 8
        for (int tau = 0; tau < 32; ++tau) {
            int t = h2[tau][e]; h2[tau][e] = run; run += t;
        }
    }
    __syncthreads();

    for (int tau = wv; tau < 32; tau += 4) {
        int c1 = h1[tau][lane], c2 = h2[tau][lane];
        const int* p = &sr[tau * 64];
        const int gbase = b * NPB + tau * 64;
        #pragma unroll 4
        for (int j = 0; j < 64; ++j) {
            int r = p[j];
            if ((r & 255) == lane) pos1[gbase + j] = c1++;
            if ((r >> 16) && (((r >> 8) & 255) == lane)) pos2raw[gbase + j] = c2++;
        }
    }
}

// K3: single streaming pass writes BOTH halves (dispatch + combine) for 4
// tokens per block; zero fast-path; block 4096 computes the loss.
__global__ __launch_bounds__(256) void k_out(
    const int* __restrict__ route,
    const int* __restrict__ pos1, const int* __restrict__ pos2raw,
    const int* __restrict__ cnt1tot,
    const float2* __restrict__ g12, const float* __restrict__ part,
    float* __restrict__ out)
{
    const int tid = threadIdx.x;
    const int bid = blockIdx.x;

    if (bid == 4096) {
        __shared__ float red[4];
        float v = 0.f;
        for (int p = tid; p < 512; p += 256) {
            int b = p >> 6, e = p & 63;
            float s = 0.f;
            #pragma unroll 8
            for (int c = 0; c < 32; ++c) s += part[((b << 5) + c) * 64 + e];
            v += s * (float)cnt1tot[p];
        }
        #pragma unroll
        for (int off = 32; off; off >>= 1) v += __shfl_xor(v, off, 64);
        if ((tid & 63) == 0) red[tid >> 6] = v;
        __syncthreads();
        if (tid == 0)
            out[2 * SOUT] = (red[0] + red[1] + red[2] + red[3]) * (1.0f / 524288.0f);
        return;
    }

    const int tg = bid * 4;

    __shared__ int   se[4][2];
    __shared__ float sv[4][2];

    if (tid < 4) {
        int t = tg + tid;
        int b = t >> 11;
        int r  = route[t];
        int i1 = r & 255, i2 = (r >> 8) & 255, k2 = (r >> 16);
        float2 g = g12[t];

        int p1 = pos1[t];
        se[tid][0] = (p1 < CAP) ? (i1 * CAP + p1) : -1;
        sv[tid][0] = g.x;

        int e2 = -1;
        if (k2) {
            int m1c = min(cnt1tot[(b << 6) + i2], CAP);
            int p2  = pos2raw[t] + m1c;
            if (p2 < CAP) e2 = i2 * CAP + p2;
        }
        se[tid][1] = e2;
        sv[tid][1] = g.y;
    }
    __syncthreads();

    vf4* dbase = (vf4*)(out + (size_t)tg * ROWF);
    vf4* cbase = (vf4*)(out + (size_t)SOUT + (size_t)tg * ROWF);
    #pragma unroll
    for (int t = 0; t < 4; ++t) {
        const int   e1 = se[t][0], e2 = se[t][1];
        const float v1 = sv[t][0], v2 = sv[t][1];
        const int   q1 = e1 >> 2, q2 = e2 >> 2;   // vf4 slot containing e1/e2
        vf4* pd = dbase + (size_t)t * (ROWF / 4);
        vf4* pc = cbase + (size_t)t * (ROWF / 4);
        for (int s = tid; s < ROWF / 4; s += 256) {
            vf4 d = {0.f, 0.f, 0.f, 0.f};
            vf4 c = {0.f, 0.f, 0.f, 0.f};
            if (s == q1) { d[e1 & 3] = 1.f; c[e1 & 3] = v1; }   // rare
            if (s == q2) { d[e2 & 3] = 1.f; c[e2 & 3] = v2; }   // rare
            __builtin_nontemporal_store(d, pd + s);
            __builtin_nontemporal_store(c, pc + s);
        }
    }
}

extern "C" void kernel_launch(void* const* d_in, const int* in_sizes, int n_in,
                              void* d_out, int out_size, void* d_ws, size_t ws_size,
                              hipStream_t stream) {
    (void)in_sizes; (void)n_in; (void)ws_size; (void)out_size;
    const float* x     = (const float*)d_in[0];
    const float* w     = (const float*)d_in[1];
    const float* noise = (const float*)d_in[2];
    float* out = (float*)d_out;
    char*  ws  = (char*)d_ws;

    int*    route   = (int*)   (ws + OFF_ROUTE);
    int*    pos1    = (int*)   (ws + OFF_POS1);
    int*    pos2raw = (int*)   (ws + OFF_POS2);
    int*    cnt1tot = (int*)   (ws + OFF_CNT1);
    float*  part    = (float*) (ws + OFF_PART);
    float2* g12     = (float2*)(ws + OFF_G12);

    k_gate<<<dim3(NTOK / 64), dim3(256), 0, stream>>>(
        x, w, noise, route, g12, part);
    k_pos<<<dim3(8), dim3(256), 0, stream>>>(
        route, pos1, pos2raw, cnt1tot);
    k_out<<<dim3(4097), dim3(256), 0, stream>>>(
        route, pos1, pos2raw, cnt1tot, g12, part, out);
}